// Round 7
// baseline (163.769 us; speedup 1.0000x reference)
//
#include <hip/hip_runtime.h>
#include <stdint.h>

#define IN_DIM 512
#define CB 8192
#define CD 16
#define NROWS 32768
#define DELTAQ 8e-3f
#define FMAXV 3.402823466e38f

typedef short bf16x8 __attribute__((ext_vector_type(8)));
typedef float f32x4 __attribute__((ext_vector_type(4)));

__device__ inline unsigned short f2bf(float x) {
    unsigned u = __float_as_uint(x);
    unsigned r = u + 0x7FFFu + ((u >> 16) & 1u);   // RNE
    return (unsigned short)(r >> 16);
}
__device__ inline float bf2f(unsigned short h) { return __uint_as_float(((unsigned)h) << 16); }
__device__ inline unsigned umin32(unsigned a, unsigned b) { return a < b ? a : b; }
__device__ inline unsigned umax32(unsigned a, unsigned b) { return a > b ? a : b; }
__device__ inline unsigned long long shfl_xor_u64(unsigned long long x, int m) {
    double d = __shfl_xor(__longlong_as_double((long long)x), m, 64);
    return (unsigned long long)__double_as_longlong(d);
}
// median(a,b,c): with invariant s1<=s2, med3(s1,s2,k) == umin(s2, umax(k, s1)) bit-exactly.
__device__ inline unsigned med3_u32(unsigned a, unsigned b, unsigned c) {
    unsigned d;
    asm("v_med3_u32 %0, %1, %2, %3" : "=v"(d) : "v"(a), "v"(b), "v"(c));
    return d;
}

// ---------------- K0: prep — csq (R1-bit-exact) + csq4 broadcast table + packed B + counter ----------------
__global__ __launch_bounds__(256) void prep_kernel(const float* __restrict__ cb,
                                                   float* __restrict__ csq,
                                                   f32x4* __restrict__ csq4,
                                                   bf16x8* __restrict__ Bp,
                                                   int* __restrict__ counter) {
    int id = blockIdx.x * 256 + threadIdx.x;  // 0..32767
    if (id == 0) counter[0] = 0;
    if (id < CB) {   // SOURCE-IDENTICAL csq expression (bit-exact vs R1)
        const float4* p = (const float4*)(cb + (size_t)id * CD);
        float s = 0.f;
#pragma unroll
        for (int j = 0; j < 4; ++j) {
            float4 v = p[j];
            s += v.x * v.x + v.y * v.y + v.z * v.z + v.w * v.w;
        }
        csq[id] = s;
        float so = s + 256.0f;     // positive-score offset (approx path only)
        f32x4 v4 = {so, so, so, so};
        csq4[id] = v4;             // pre-broadcast MFMA C-operand
    }
    int slot = id & 63;
    int nt = id >> 6;
    int q = slot >> 4;
    int n = nt * 16 + (slot & 15);
    int d0 = (q & 1) * 8;
    bool lo = (q < 2);          // k<16 -> c1[d], k>=16 -> c2[d]
    const float* src = cb + (size_t)n * CD + d0;
    bf16x8 v;
#pragma unroll
    for (int j = 0; j < 8; ++j) {
        float x = src[j];
        unsigned short a = f2bf(x);
        unsigned short b = f2bf(x - bf2f(a));
        v[j] = (short)(lo ? a : b);
    }
    Bp[id] = v;
}

// ---------------- K1: FUSED proj+scan — 512 blocks x 512 thr, 64 rows/block ----------------
// Proj phase: full W staged once (32KB LDS); 4 input chunks looped through LIN; wave wv owns
// dims [2wv, 2wv+2) for all 64 rows (lane=row). Per-(row,dim) arithmetic is EXPRESSION-IDENTICAL
// to the prior proj kernel (serial j-fold per chunk, ((c0+c1)+c2)+c3 chunk fold, *(-2)) ->
// tprime bit-exact. tprime stored to global for the fallback (same bits, already folded).
// Scan phase: unchanged G=4 packed-B scan (wave e scans eighth e; med3 second-min).
__global__ __launch_bounds__(512, 4) void fused_kernel(
        const float* __restrict__ in, const float* __restrict__ W,
        float* __restrict__ tpout, const f32x4* __restrict__ csq4,
        const bf16x8* __restrict__ Bp, int* __restrict__ out,
        int* __restrict__ queue, int* __restrict__ counter) {
    __shared__ float4 LIN[2048];        // [o=0..31][r=0..63] swizzled, reused per chunk
    __shared__ float4 WL[16 * 129];     // full W: [d][c*32+j] with pad, row stride 129 f4
    __shared__ float tbuf[64][17];
    __shared__ unsigned long long m_k[64][8];
    __shared__ unsigned m_s2[64][8];

    int tid = threadIdx.x;
    int lane = tid & 63;
    int wv = __builtin_amdgcn_readfirstlane(tid >> 6);   // wave 0..7
    int rowbase = blockIdx.x * 64;
    const float4* inp4 = (const float4*)in;
    const float4* W4 = (const float4*)W;

    // stage full W once: 16 x 128 f4
#pragma unroll
    for (int u = 0; u < 4; ++u) {
        int f = tid + u * 512;          // 0..2047
        int d = f >> 7, k = f & 127;
        WL[d * 129 + k] = W4[(size_t)d * 128 + k];
    }

    // ---- proj phase: 4 chunks, serial fold (bit-exact DAG) ----
    float fold0 = 0.f, fold1 = 0.f;
    for (int c = 0; c < 4; ++c) {
        __syncthreads();                // also covers WL staging before first read
#pragma unroll
        for (int u = 0; u < 4; ++u) {
            int f = tid + u * 512;      // 0..2047
            int o = f & 31, r = f >> 5; // consecutive tid -> consecutive o: coalesced
            LIN[o * 64 + (r ^ (o & 7))] = inp4[(size_t)(rowbase + r) * 128 + c * 32 + o];
        }
        __syncthreads();
        float acc0 = 0.f, acc1 = 0.f;
#pragma unroll 4
        for (int j = 0; j < 32; ++j) {
            float4 v = LIN[j * 64 + (lane ^ (j & 7))];
            float4 w0 = WL[(2 * wv) * 129 + c * 32 + j];       // wave-uniform -> broadcast
            float4 w1 = WL[(2 * wv + 1) * 129 + c * 32 + j];
            acc0 += v.x * w0.x + v.y * w0.y + v.z * w0.z + v.w * w0.w;
            acc1 += v.x * w1.x + v.y * w1.y + v.z * w1.z + v.w * w1.w;
        }
        fold0 += acc0;                  // ((c0+c1)+c2)+c3 — same order as prior combine
        fold1 += acc1;
    }
    float t0 = -2.f * fold0;
    float t1 = -2.f * fold1;
    tbuf[lane][2 * wv] = t0;
    tbuf[lane][2 * wv + 1] = t1;
    {   // store tprime for the fallback (identical bits to tbuf)
        float* tp = tpout + (size_t)(rowbase + lane) * CD + 2 * wv;
        tp[0] = t0;
        tp[1] = t1;
    }
    __syncthreads();

    // ---- scan phase: unchanged G=4 packed-B scan ----
    int e = wv;                          // eighth 0..7
    int q = lane >> 4;
    int col = lane & 15;
    int d0 = (q & 1) * 8;
    bool lo = (q < 2);

    bf16x8 A1[4], A2[4];   // per rowgroup: A1=[t1|t1], A2=[t2|0]
#pragma unroll
    for (int g = 0; g < 4; ++g) {
        int arow = 16 * g + col;
#pragma unroll
        for (int j = 0; j < 8; ++j) {
            float x = tbuf[arow][d0 + j];
            unsigned short h1 = f2bf(x);
            unsigned short h2 = f2bf(x - bf2f(h1));
            A1[g][j] = (short)h1;
            A2[g][j] = (short)(lo ? h2 : 0);
        }
    }

    unsigned s1[4][4], s2[4][4];
#pragma unroll
    for (int g = 0; g < 4; ++g)
#pragma unroll
        for (int r = 0; r < 4; ++r) { s1[g][r] = 0xFFFFFFFFu; s2[g][r] = 0xFFFFFFFFu; }

    int nt0 = e * 64;
    const bf16x8* pb = Bp + (size_t)nt0 * 64 + lane;
    const f32x4* csqp = csq4 + nt0 * 16 + col;

    for (int tc = 0; tc < 16; ++tc) {
        bf16x8 bv[4];
        f32x4 iv[4];
#pragma unroll
        for (int u = 0; u < 4; ++u) {
            bv[u] = pb[u * 64];
            iv[u] = csqp[u * 16];
        }
#pragma unroll
        for (int u = 0; u < 4; ++u) {
            unsigned tt = (unsigned)(tc * 4 + u);
#pragma unroll
            for (int g = 0; g < 4; ++g) {   // 4 independent MFMA-pair chains per b
                f32x4 acc = __builtin_amdgcn_mfma_f32_16x16x32_bf16(A1[g], bv[u], iv[u], 0, 0, 0);
                acc = __builtin_amdgcn_mfma_f32_16x16x32_bf16(A2[g], bv[u], acc, 0, 0, 0);
#pragma unroll
                for (int r = 0; r < 4; ++r) {
                    unsigned k = (__float_as_uint(acc[r]) & 0xFFFFFFC0u) | tt;
                    s2[g][r] = med3_u32(s1[g][r], s2[g][r], k);  // == umin(s2, umax(k, OLD s1))
                    s1[g][r] = umin32(s1[g][r], k);
                }
            }
        }
        pb += 256;     // 4 tiles * 64 fragments
        csqp += 64;    // 4 tiles * 16 cols
    }

    // cross-col reduce; FK orders (qscore, e, tile, col) = (qscore, code)
#pragma unroll
    for (int g = 0; g < 4; ++g)
#pragma unroll
        for (int r = 0; r < 4; ++r) {
            unsigned long long FK = ((unsigned long long)(s1[g][r] & 0xFFFFFFC0u) << 13)
                                  | ((unsigned long long)e << 10)
                                  | ((unsigned long long)(s1[g][r] & 63u) << 4)
                                  | (unsigned long long)col;
            unsigned s2q = s2[g][r] & 0xFFFFFFC0u;
#pragma unroll
            for (int m = 1; m < 16; m <<= 1) {
                unsigned long long oFK = shfl_xor_u64(FK, m);
                unsigned os2 = (unsigned)__shfl_xor((int)s2q, m, 64);
                unsigned qa = (unsigned)(FK >> 13);
                unsigned qb = (unsigned)(oFK >> 13);
                s2q = umin32(umin32(s2q, os2), umax32(qa, qb));
                FK = oFK < FK ? oFK : FK;
            }
            if (col == 0) {
                int rl = 16 * g + 4 * q + r;   // C/D row = quad*4 + reg; rl in 0..63
                m_k[rl][e] = FK;
                m_s2[rl][e] = s2q;
            }
        }
    __syncthreads();

    if (tid < 64) {
        unsigned long long mFK = m_k[tid][0];
        unsigned g1 = (unsigned)(m_k[tid][0] >> 13);
        unsigned g2 = m_s2[tid][0];
#pragma unroll
        for (int ee = 1; ee < 8; ++ee) {
            unsigned long long F = m_k[tid][ee];
            unsigned u = (unsigned)(F >> 13);
            if (u < g1) { g2 = g1; g1 = u; } else { g2 = umin32(g2, u); }
            g2 = umin32(g2, m_s2[tid][ee]);
            mFK = F < mFK ? F : mFK;
        }
        int ccol = (int)(mFK & 15ull);
        int ctile = (int)((mFK >> 4) & 63ull);
        int ce = (int)((mFK >> 10) & 7ull);
        int row = rowbase + tid;
        out[row] = ((ce * 64 + ctile) << 4) | ccol;
        if (__uint_as_float(g2) - __uint_as_float(g1) < DELTAQ) {
            int pos = atomicAdd(counter, 1);
            queue[pos] = row;
        }
    }
}

// ---------------- K2: fallback — R1's fp32 arithmetic, bit-exact, queue-driven, wide grid ----------------
// Reads the stored tprime (same bits as the fused kernel's fold) — no recompute.
__global__ __launch_bounds__(256) void fallback_kernel(const float* __restrict__ tpout,
                                                       const float* __restrict__ cb,
                                                       const float* __restrict__ csq,
                                                       const int* __restrict__ queue,
                                                       const int* __restrict__ counter,
                                                       int* __restrict__ out) {
    __shared__ unsigned long long red[4];
    int nq = counter[0];
    int tid = threadIdx.x;
    int lane = tid & 63;
    int w = tid >> 6;

    for (int qi = blockIdx.x; qi < nq; qi += 2048) {
        int row = queue[qi];
        const float* tpp = tpout + (size_t)row * CD;
        float tp[16];
#pragma unroll
        for (int d = 0; d < 16; ++d) tp[d] = tpp[d];   // uniform -> broadcast

        float best = FMAXV;
        int bidx = 0;
#pragma unroll 2
        for (int i = 0; i < 32; ++i) {
            int k = tid + 256 * i;            // ascending per thread
            const float* cp = cb + (size_t)k * CD;
            float s = csq[k];
#pragma unroll
            for (int d = 0; d < 16; ++d) s += tp[d] * cp[d];
            if (s < best) { best = s; bidx = k; }
        }
        unsigned u = __float_as_uint(best);
        u = (u & 0x80000000u) ? ~u : (u | 0x80000000u);
        unsigned long long key = ((unsigned long long)u << 32) | (unsigned)bidx;
#pragma unroll
        for (int m = 1; m < 64; m <<= 1) {
            unsigned long long o = shfl_xor_u64(key, m);
            key = o < key ? o : key;
        }
        if (lane == 0) red[w] = key;
        __syncthreads();
        if (tid == 0) {
            unsigned long long mm = red[0];
#pragma unroll
            for (int i = 1; i < 4; ++i) { unsigned long long x = red[i]; mm = x < mm ? x : mm; }
            out[row] = (int)(mm & 0xFFFFFFFFull);
        }
        __syncthreads();
    }
}

extern "C" void kernel_launch(void* const* d_in, const int* in_sizes, int n_in,
                              void* d_out, int out_size, void* d_ws, size_t ws_size,
                              hipStream_t stream) {
    const float* input = (const float*)d_in[0];  // (8,4096,512) fp32
    const float* W     = (const float*)d_in[1];  // (16,512) fp32
    const float* cb    = (const float*)d_in[2];  // (8192,16) fp32
    int* out = (int*)d_out;                      // (32768,) int32 labels

    float*  tpout   = (float*)d_ws;                       // 2 MB
    float*  csq     = tpout + (size_t)NROWS * CD;         // 32 KB
    f32x4*  csq4    = (f32x4*)(csq + CB);                 // 128 KB
    bf16x8* Bp      = (bf16x8*)((float*)csq4 + 4 * CB);   // 512 KB
    int*    counter = (int*)(Bp + 32768);
    int*    queue   = counter + 16;                       // 128 KB

    prep_kernel<<<32768 / 256, 256, 0, stream>>>(cb, csq, csq4, Bp, counter);
    fused_kernel<<<NROWS / 64, 512, 0, stream>>>(input, W, tpout, csq4, Bp, out, queue, counter);
    fallback_kernel<<<2048, 256, 0, stream>>>(tpout, cb, csq, queue, counter, out);
}